// Round 15
// baseline (290.707 us; speedup 1.0000x reference)
//
#include <hip/hip_runtime.h>

#define HDIM 96
#define LSTR 104   // LDS row stride (bf16) for concat kernel staging
#define NBIN 64

typedef __attribute__((ext_vector_type(8))) short bf16x8;   // 8 bf16 = 4 VGPRs
typedef __attribute__((ext_vector_type(4))) float f32x4;

__device__ __forceinline__ unsigned short bf16rne(float x) {
  const unsigned u = __float_as_uint(x);
  return (unsigned short)((u + 0x7fff + ((u >> 16) & 1)) >> 16);
}

// fp32 -> (hi, lo) truncated bf16 pair; x ~= hi + lo with ~2^-16 rel error
__device__ __forceinline__ void split2(float x, unsigned short& hi, unsigned short& lo) {
  const unsigned u = __float_as_uint(x);
  hi = (unsigned short)(u >> 16);
  const float xhi = __uint_as_float(u & 0xffff0000u);
  lo = (unsigned short)(__float_as_uint(x - xhi) >> 16);
}

__global__ void zero_k(int* __restrict__ p, int n) {
  int i = blockIdx.x * blockDim.x + threadIdx.x;
  if (i < n) p[i] = 0;
}

__global__ void deg_rank_k(const int* __restrict__ dst, int* __restrict__ indeg,
                           int* __restrict__ rank, int e) {
  int i = blockIdx.x * blockDim.x + threadIdx.x;
  if (i < e) rank[i] = atomicAdd(&indeg[dst[i]], 1);
}

__device__ __forceinline__ int wave_incl_scan(int v, int lane) {
#pragma unroll
  for (int off = 1; off < 64; off <<= 1) {
    int t = __shfl_up(v, off, 64);
    if (lane >= off) v += t;
  }
  return v;
}

// Phase A: bsum[b] = chunk sum of indeg; fused degree histogram -> bins.
__global__ __launch_bounds__(1024) void scan_a_k(const int* __restrict__ indeg,
                                                 int* __restrict__ bsum,
                                                 int* __restrict__ bins, int n) {
  __shared__ int ws[16];
  __shared__ int lh[NBIN];
  const int tid = threadIdx.x;
  if (tid < NBIN) lh[tid] = 0;
  const int i = blockIdx.x * 1024 + tid;
  const int v = (i < n) ? indeg[i] : 0;
  int s = v;
#pragma unroll
  for (int off = 32; off; off >>= 1) s += __shfl_down(s, off, 64);
  if ((tid & 63) == 0) ws[tid >> 6] = s;
  __syncthreads();                       // guards ws + lh zero
  if (tid < 16) {
    int q = ws[tid];
#pragma unroll
    for (int off = 8; off; off >>= 1) q += __shfl_down(q, off, 16);
    if (tid == 0) bsum[blockIdx.x] = q;
  }
  if (i < n) atomicAdd(&lh[min(v, NBIN - 1)], 1);
  __syncthreads();
  if (tid < NBIN && lh[tid]) atomicAdd(&bins[tid], lh[tid]);
}

// Phase B: chunk-sum exclusive scan -> bbase; offsets[n]=total; fused bin scan
// (descending-degree base) -> bincur.
__global__ __launch_bounds__(1024) void scan_b_k(const int* __restrict__ bsum,
                                                 int* __restrict__ bbase,
                                                 int* __restrict__ offsets,
                                                 const int* __restrict__ bins,
                                                 int* __restrict__ bincur, int nb, int n) {
  __shared__ int ws[16];
  const int tid = threadIdx.x, lane = tid & 63, w = tid >> 6;
  const int v = (tid < nb) ? bsum[tid] : 0;
  int incl = wave_incl_scan(v, lane);
  if (lane == 63) ws[w] = incl;
  __syncthreads();
  if (tid < 16) {
    int s = ws[tid];
#pragma unroll
    for (int off = 1; off < 16; off <<= 1) {
      int t = __shfl_up(s, off, 16);
      if (tid >= off) s += t;
    }
    ws[tid] = s;
  }
  __syncthreads();
  incl += (w > 0 ? ws[w - 1] : 0);
  if (tid < nb) bbase[tid] = incl - v;
  if (tid == 0) offsets[n] = ws[15];
  if (tid < NBIN) {
    const int c = bins[tid];
    int binc = wave_incl_scan(c, tid);
    const int total = __shfl(binc, 63, 64);
    bincur[tid] = total - binc;          // count of nodes in strictly-higher bins
  }
}

// Phase C: offsets + dis; fused degree-bucket placement -> perm (desc order).
__global__ __launch_bounds__(1024) void scan_c_k(const int* __restrict__ indeg,
                                                 const int* __restrict__ bbase,
                                                 int* __restrict__ offsets,
                                                 float* __restrict__ dis,
                                                 int* __restrict__ bincur,
                                                 int* __restrict__ perm, int n) {
  __shared__ int ws[16];
  __shared__ int lh[NBIN], lbase[NBIN], lcur[NBIN];
  const int tid = threadIdx.x, lane = tid & 63, w = tid >> 6;
  if (tid < NBIN) { lh[tid] = 0; lcur[tid] = 0; }
  const int i = blockIdx.x * 1024 + tid;
  const int v = (i < n) ? indeg[i] : 0;
  int incl = wave_incl_scan(v, lane);
  if (lane == 63) ws[w] = incl;
  __syncthreads();                       // guards ws + lh/lcur zero
  if (tid < 16) {
    int s = ws[tid];
#pragma unroll
    for (int off = 1; off < 16; off <<= 1) {
      int t = __shfl_up(s, off, 16);
      if (tid >= off) s += t;
    }
    ws[tid] = s;
  }
  __syncthreads();
  incl += (w > 0 ? ws[w - 1] : 0);
  if (i < n) {
    offsets[i] = bbase[blockIdx.x] + incl - v;
    dis[i] = rsqrtf((float)(1 + v));
  }
  const int bin = (i < n) ? min(v, NBIN - 1) : -1;
  if (bin >= 0) atomicAdd(&lh[bin], 1);
  __syncthreads();
  if (tid < NBIN) lbase[tid] = lh[tid] ? atomicAdd(&bincur[tid], lh[tid]) : 0;
  __syncthreads();
  if (bin >= 0) {
    const int r = atomicAdd(&lcur[bin], 1);
    perm[lbase[bin] + r] = i;
  }
}

__global__ void place_k(const int* __restrict__ src, const int* __restrict__ dst,
                        const int* __restrict__ rank, const int* __restrict__ offsets,
                        int* __restrict__ csr_src, int e) {
  int i = blockIdx.x * blockDim.x + threadIdx.x;
  if (i >= e) return;
  int d = dst[i];
  atomicExch(&csr_src[offsets[d] + rank[i]], src[i]);
}

// Pre-split ALL weights once into bf16 hi/lo, B-fragment-ready [n][k] layout.
// 5 tiles of 96x96: 0=W_local, 1=W_g1, 2=W_g2, 3=W_fuse[0:96], 4=W_fuse[96:192].
__global__ void split_w_k(const float* __restrict__ W0, const float* __restrict__ W1,
                          const float* __restrict__ W2, const float* __restrict__ W3,
                          unsigned short* __restrict__ dH, unsigned short* __restrict__ dL) {
  const int t = blockIdx.x * blockDim.x + threadIdx.x;
  if (t >= 5 * 9216) return;
  const int tile = t / 9216, r = t % 9216;
  const int nn = r / 96, k = r % 96;
  const float* W = (tile == 0) ? W0 : (tile == 1) ? W1 : (tile == 2) ? W2 : W3;
  const int row = (tile == 4) ? 96 + k : k;
  unsigned short h, l;
  split2(W[row * 96 + nn], h, l);
  dH[t] = h;
  dL[t] = l;
}

// o[i,:] = bf16( dis[i] * x[i,:] )
__global__ void scale_bf16_k(const float* __restrict__ x, const float* __restrict__ dis,
                             unsigned short* __restrict__ o, int n) {
  int t = blockIdx.x * blockDim.x + threadIdx.x;
  if (t >= n * 24) return;
  const float d = dis[t / 24];
  float4 v = ((const float4*)x)[t];
  ushort4 h;
  h.x = bf16rne(v.x * d); h.y = bf16rne(v.y * d);
  h.z = bf16rne(v.z * d); h.w = bf16rne(v.w * d);
  ((ushort4*)o)[t] = h;
}

__device__ __forceinline__ void acc8(float* a, uint4 p) {
  a[0] += __uint_as_float(p.x << 16);
  a[1] += __uint_as_float(p.x & 0xffff0000u);
  a[2] += __uint_as_float(p.y << 16);
  a[3] += __uint_as_float(p.y & 0xffff0000u);
  a[4] += __uint_as_float(p.z << 16);
  a[5] += __uint_as_float(p.z & 0xffff0000u);
  a[6] += __uint_as_float(p.w << 16);
  a[7] += __uint_as_float(p.w & 0xffff0000u);
}

// ---- fused gather + MFMA, 2-wave edge-split per 16-node group ----
// Block 256 = 4 waves = 2 groups x 2 halves. Group g covers nodes
// perm[blockIdx*32+16g .. +16). Wave half h gathers its half of each node's
// edges into A-frag layout (m=lane&15, k=32kc+8quad+j); h=1 dumps partials to
// LDS (stride 25 -> conflict-free), h=0 combines + *dis. B-frags load straight
// from pre-split global W (L1/L2-resident; no W LDS). DUAL: h=0 runs W set0
// (-> relu+split out), h=1 runs W set1 (-> dis*relu bf16 msg) CONCURRENTLY.
// Non-DUAL: h=1 retires after the partial dump.
template<bool DUAL>
__global__ __launch_bounds__(256, 5) void gat_gemm_k(
    const int* __restrict__ perm,
    const int* __restrict__ csr_src, const int* __restrict__ offsets,
    const float* __restrict__ dis, const unsigned short* __restrict__ hp,
    const unsigned short* __restrict__ WH0, const unsigned short* __restrict__ WL0,
    const float* __restrict__ b0,
    const unsigned short* __restrict__ WH1, const unsigned short* __restrict__ WL1,
    const float* __restrict__ b1,
    unsigned short* __restrict__ outH, unsigned short* __restrict__ outL,
    unsigned short* __restrict__ outMsg, int M) {
  __shared__ float part[2 * 64 * 25];   // 12.8 KB; stride 25 words -> 2-way (free)
  const int t = threadIdx.x;
  const int lane = t & 63, wv = t >> 6;
  const int g = wv & 1, h = wv >> 1;
  const int m = lane & 15, quad = lane >> 4;
  const int row0 = blockIdx.x * 32 + 16 * g;
  const int j = row0 + m;
  const int node = (j < M) ? perm[j] : -1;

  float a[3][8];
#pragma unroll
  for (int c = 0; c < 3; c++)
#pragma unroll
    for (int jj = 0; jj < 8; jj++) a[c][jj] = 0.f;

  if (node >= 0) {
    const int beg = offsets[node], end = offsets[node + 1];
    const int mid = beg + ((end - beg + 1) >> 1);
    int i, stop;
    if (h == 0) {
      const unsigned short* selfp = hp + (size_t)node * HDIM + 8 * quad;
      acc8(a[0], *(const uint4*)(selfp));
      acc8(a[1], *(const uint4*)(selfp + 32));
      acc8(a[2], *(const uint4*)(selfp + 64));
      i = beg; stop = mid;
    } else {
      i = mid; stop = end;
    }
    for (; i + 1 < stop; i += 2) {
      const unsigned short* p0 = hp + (size_t)csr_src[i] * HDIM + 8 * quad;
      const unsigned short* p1 = hp + (size_t)csr_src[i + 1] * HDIM + 8 * quad;
      const uint4 v00 = *(const uint4*)(p0), v01 = *(const uint4*)(p0 + 32), v02 = *(const uint4*)(p0 + 64);
      const uint4 v10 = *(const uint4*)(p1), v11 = *(const uint4*)(p1 + 32), v12 = *(const uint4*)(p1 + 64);
      acc8(a[0], v00); acc8(a[1], v01); acc8(a[2], v02);
      acc8(a[0], v10); acc8(a[1], v11); acc8(a[2], v12);
    }
    if (i < stop) {
      const unsigned short* p0 = hp + (size_t)csr_src[i] * HDIM + 8 * quad;
      acc8(a[0], *(const uint4*)(p0));
      acc8(a[1], *(const uint4*)(p0 + 32));
      acc8(a[2], *(const uint4*)(p0 + 64));
    }
  }

  float* ps = &part[(g * 64 + lane) * 25];
  if (h == 1) {
#pragma unroll
    for (int c = 0; c < 3; c++) {
      *(float4*)(ps + 8 * c)     = make_float4(a[c][0], a[c][1], a[c][2], a[c][3]);
      *(float4*)(ps + 8 * c + 4) = make_float4(a[c][4], a[c][5], a[c][6], a[c][7]);
    }
  }
  __syncthreads();
  if (h == 0) {
    const float dd = (node >= 0) ? dis[node] : 0.f;
#pragma unroll
    for (int c = 0; c < 3; c++) {
      const float4 p0 = *(const float4*)(ps + 8 * c);
      const float4 p1 = *(const float4*)(ps + 8 * c + 4);
      a[c][0] = (a[c][0] + p0.x) * dd; a[c][1] = (a[c][1] + p0.y) * dd;
      a[c][2] = (a[c][2] + p0.z) * dd; a[c][3] = (a[c][3] + p0.w) * dd;
      a[c][4] = (a[c][4] + p1.x) * dd; a[c][5] = (a[c][5] + p1.y) * dd;
      a[c][6] = (a[c][6] + p1.z) * dd; a[c][7] = (a[c][7] + p1.w) * dd;
    }
    if (DUAL) {
#pragma unroll
      for (int c = 0; c < 3; c++) {
        *(float4*)(ps + 8 * c)     = make_float4(a[c][0], a[c][1], a[c][2], a[c][3]);
        *(float4*)(ps + 8 * c + 4) = make_float4(a[c][4], a[c][5], a[c][6], a[c][7]);
      }
    }
  }
  if (DUAL) {
    __syncthreads();
    if (h == 1) {
#pragma unroll
      for (int c = 0; c < 3; c++) {
        const float4 p0 = *(const float4*)(ps + 8 * c);
        const float4 p1 = *(const float4*)(ps + 8 * c + 4);
        a[c][0] = p0.x; a[c][1] = p0.y; a[c][2] = p0.z; a[c][3] = p0.w;
        a[c][4] = p1.x; a[c][5] = p1.y; a[c][6] = p1.z; a[c][7] = p1.w;
      }
    }
  } else {
    if (h == 1) return;
  }

  // split to A fragments in registers
  bf16x8 ah[3], al[3];
#pragma unroll
  for (int c = 0; c < 3; c++)
#pragma unroll
    for (int jj = 0; jj < 8; jj++) {
      unsigned short hi, lo;
      split2(a[c][jj], hi, lo);
      ah[c][jj] = (short)hi;
      al[c][jj] = (short)lo;
    }

  const unsigned short* WH = (DUAL && h) ? WH1 : WH0;
  const unsigned short* WL = (DUAL && h) ? WL1 : WL0;
  f32x4 acc[6];
#pragma unroll
  for (int c = 0; c < 6; c++) acc[c] = (f32x4){0.f, 0.f, 0.f, 0.f};
#pragma unroll
  for (int kc = 0; kc < 3; kc++) {
    const int ko = 32 * kc + 8 * quad;
#pragma unroll
    for (int c = 0; c < 6; c++) {
      const bf16x8 wh = *(const bf16x8*)(WH + (size_t)(16 * c + m) * HDIM + ko);
      const bf16x8 wl = *(const bf16x8*)(WL + (size_t)(16 * c + m) * HDIM + ko);
      acc[c] = __builtin_amdgcn_mfma_f32_16x16x32_bf16(ah[kc], wh, acc[c], 0, 0, 0);
      acc[c] = __builtin_amdgcn_mfma_f32_16x16x32_bf16(ah[kc], wl, acc[c], 0, 0, 0);
      acc[c] = __builtin_amdgcn_mfma_f32_16x16x32_bf16(al[kc], wh, acc[c], 0, 0, 0);
    }
  }

  // epilogue: D col=16c+m, tile-row = 4quad+r -> node = perm[row0+4quad+r]
  const int rbase = row0 + 4 * quad;
  int rows[4];
#pragma unroll
  for (int r = 0; r < 4; r++) rows[r] = (rbase + r < M) ? perm[rbase + r] : -1;
  const float* bias = (DUAL && h) ? b1 : b0;
  if (!DUAL || h == 0) {
#pragma unroll
    for (int c = 0; c < 6; c++) {
      const int col = 16 * c + m;
      const float bv = bias[col];
#pragma unroll
      for (int r = 0; r < 4; r++) {
        if (rows[r] >= 0) {
          const float v = fmaxf(acc[c][r] + bv, 0.f);
          unsigned short hi, lo;
          split2(v, hi, lo);
          const size_t idx = (size_t)rows[r] * HDIM + col;
          outH[idx] = hi;
          outL[idx] = lo;
        }
      }
    }
  } else {
    float dv[4];
#pragma unroll
    for (int r = 0; r < 4; r++) dv[r] = (rows[r] >= 0) ? dis[rows[r]] : 0.f;
#pragma unroll
    for (int c = 0; c < 6; c++) {
      const int col = 16 * c + m;
      const float bv = bias[col];
#pragma unroll
      for (int r = 0; r < 4; r++) {
        if (rows[r] >= 0)
          outMsg[(size_t)rows[r] * HDIM + col] = bf16rne(fmaxf(acc[c][r] + bv, 0.f) * dv[r]);
      }
    }
  }
}

// ---- concat GEMM (copy-only staging, pre-split A and W) ----
__global__ __launch_bounds__(256) void gemm_concat_k(
    const unsigned short* __restrict__ AH0, const unsigned short* __restrict__ AL0,
    const unsigned short* __restrict__ AH1, const unsigned short* __restrict__ AL1,
    const unsigned short* __restrict__ WH, const unsigned short* __restrict__ WL,
    const float* __restrict__ bias, float* __restrict__ out, int M) {
  __shared__ __align__(16) unsigned short Ah[64 * LSTR], Al[64 * LSTR];
  __shared__ __align__(16) unsigned short Wh[96 * LSTR], Wl[96 * LSTR];
  const int t = threadIdx.x;
  const int lane = t & 63, wv = t >> 6;
  const int m = lane & 15, quad = lane >> 4;
  const int row0 = blockIdx.x * 64;

  f32x4 acc[6];
#pragma unroll
  for (int c = 0; c < 6; c++) acc[c] = (f32x4){0.f, 0.f, 0.f, 0.f};

  for (int kt = 0; kt < 2; kt++) {
    const unsigned short* AH = kt ? AH1 : AH0;
    const unsigned short* AL = kt ? AL1 : AL0;
    if (kt) __syncthreads();
    for (int u = t; u < 768; u += 256) {
      const int r = u / 12, kq = u % 12;
      uint4 vh = make_uint4(0, 0, 0, 0), vl = make_uint4(0, 0, 0, 0);
      if (row0 + r < M) {
        vh = ((const uint4*)(AH + (size_t)(row0 + r) * HDIM))[kq];
        vl = ((const uint4*)(AL + (size_t)(row0 + r) * HDIM))[kq];
      }
      *(uint4*)(&Ah[r * LSTR + 8 * kq]) = vh;
      *(uint4*)(&Al[r * LSTR + 8 * kq]) = vl;
    }
    const unsigned short* WHt = WH + (size_t)kt * 9216;
    const unsigned short* WLt = WL + (size_t)kt * 9216;
    for (int u = t; u < 1152; u += 256) {
      const int nn = u / 12, kq = u % 12;
      *(uint4*)(&Wh[nn * LSTR + 8 * kq]) = ((const uint4*)(WHt + (size_t)nn * HDIM))[kq];
      *(uint4*)(&Wl[nn * LSTR + 8 * kq]) = ((const uint4*)(WLt + (size_t)nn * HDIM))[kq];
    }
    __syncthreads();
#pragma unroll
    for (int kc = 0; kc < 3; kc++) {
      const int ko = 32 * kc + 8 * quad;
      const bf16x8 ah = *(const bf16x8*)(&Ah[(16 * wv + m) * LSTR + ko]);
      const bf16x8 al = *(const bf16x8*)(&Al[(16 * wv + m) * LSTR + ko]);
#pragma unroll
      for (int c = 0; c < 6; c++) {
        const bf16x8 wh = *(const bf16x8*)(&Wh[(16 * c + m) * LSTR + ko]);
        const bf16x8 wl = *(const bf16x8*)(&Wl[(16 * c + m) * LSTR + ko]);
        acc[c] = __builtin_amdgcn_mfma_f32_16x16x32_bf16(ah, wh, acc[c], 0, 0, 0);
        acc[c] = __builtin_amdgcn_mfma_f32_16x16x32_bf16(ah, wl, acc[c], 0, 0, 0);
        acc[c] = __builtin_amdgcn_mfma_f32_16x16x32_bf16(al, wh, acc[c], 0, 0, 0);
      }
    }
  }

  const int rbase = row0 + 16 * wv + 4 * quad;
#pragma unroll
  for (int c = 0; c < 6; c++) {
    const int col = 16 * c + m;
    const float bv = bias[col];
#pragma unroll
    for (int r = 0; r < 4; r++) {
      const int row = rbase + r;
      if (row < M) out[(size_t)row * HDIM + col] = acc[c][r] + bv;
    }
  }
}

extern "C" void kernel_launch(void* const* d_in, const int* in_sizes, int n_in,
                              void* d_out, int out_size, void* d_ws, size_t ws_size,
                              hipStream_t stream) {
  const float* x       = (const float*)d_in[0];
  const int*   edge    = (const int*)d_in[1];
  const float* W_local = (const float*)d_in[2];
  const float* b_local = (const float*)d_in[3];
  const float* W_g1    = (const float*)d_in[4];
  const float* b_g1    = (const float*)d_in[5];
  const float* W_g2    = (const float*)d_in[6];
  const float* b_g2    = (const float*)d_in[7];
  const float* W_fuse  = (const float*)d_in[8]; // [192, 96] row-major
  const float* b_fuse  = (const float*)d_in[9];
  float* out = (float*)d_out;

  const int n = in_sizes[0] / HDIM;
  const int e = in_sizes[1] / 2;
  const int* src = edge;
  const int* dst = edge + e;
  const int nb = (n + 1023) / 1024;

  char* ws = (char*)d_ws;
  auto alloc = [&](size_t bytes) { char* p = ws; ws += (bytes + 255) & ~(size_t)255; return p; };
  int*   meta    = (int*)alloc(((size_t)n + NBIN) * 4);   // indeg | bins (zeroed together)
  int*   indeg   = meta;
  int*   bins    = meta + n;
  float* dis     = (float*)alloc((size_t)n * 4);
  int*   offsets = (int*)alloc((size_t)(n + 1) * 4);
  int*   bsum    = (int*)alloc((size_t)nb * 4);
  int*   bbase   = (int*)alloc((size_t)nb * 4);
  int*   bincur  = (int*)alloc(NBIN * 4);
  int*   rank    = (int*)alloc((size_t)e * 4);
  int*   csr_src = (int*)alloc((size_t)e * 4);
  int*   perm    = (int*)alloc((size_t)n * 4);
  const size_t mat16 = (size_t)n * HDIM * 2;
  unsigned short* msgX = (unsigned short*)alloc(mat16);   // x' messages
  unsigned short* msgG = (unsigned short*)alloc(mat16);   // g1' messages
  unsigned short* locH = (unsigned short*)alloc(mat16);   // local hi/lo
  unsigned short* locL = (unsigned short*)alloc(mat16);
  unsigned short* g2H  = (unsigned short*)alloc(mat16);   // g2 hi/lo
  unsigned short* g2L  = (unsigned short*)alloc(mat16);
  unsigned short* wH   = (unsigned short*)alloc(5 * 9216 * 2);
  unsigned short* wL   = (unsigned short*)alloc(5 * 9216 * 2);

  zero_k<<<(n + NBIN + 255) / 256, 256, 0, stream>>>(meta, n + NBIN);
  deg_rank_k<<<(e + 255) / 256, 256, 0, stream>>>(dst, indeg, rank, e);
  scan_a_k<<<nb, 1024, 0, stream>>>(indeg, bsum, bins, n);
  scan_b_k<<<1, 1024, 0, stream>>>(bsum, bbase, offsets, bins, bincur, nb, n);
  scan_c_k<<<nb, 1024, 0, stream>>>(indeg, bbase, offsets, dis, bincur, perm, n);
  place_k<<<(e + 255) / 256, 256, 0, stream>>>(src, dst, rank, offsets, csr_src, e);
  split_w_k<<<(5 * 9216 + 255) / 256, 256, 0, stream>>>(W_local, W_g1, W_g2, W_fuse, wH, wL);

  const int gb2 = (n + 31) / 32;       // fused kernels: 32 nodes/block
  const int gb = (n + 63) / 64;        // concat: 64 rows/block

  // x' = bf16(dis·x)
  scale_bf16_k<<<(n * 24 + 255) / 256, 256, 0, stream>>>(x, dis, msgX, n);
  // hop 1 fused (edge-split): local = split(relu(ax@Wl+b)); g1' = msg(dis·relu(ax@Wg1+b))
  gat_gemm_k<true><<<gb2, 256, 0, stream>>>(perm, csr_src, offsets, dis, msgX,
                                            wH, wL, b_local,
                                            wH + 9216, wL + 9216, b_g1,
                                            locH, locL, msgG, n);
  // hop 2 fused: g2 = split(relu(ag2@Wg2+b))
  gat_gemm_k<false><<<gb2, 256, 0, stream>>>(perm, csr_src, offsets, dis, msgG,
                                             wH + 2 * 9216, wL + 2 * 9216, b_g2,
                                             nullptr, nullptr, nullptr,
                                             g2H, g2L, nullptr, n);
  // out = [local | g2] @ W_fuse + b_fuse
  gemm_concat_k<<<gb, 256, 0, stream>>>(locH, locL, g2H, g2L,
                                        wH + 3 * 9216, wL + 3 * 9216, b_fuse, out, n);
}

// Round 16
// 284.163 us; speedup vs baseline: 1.0230x; 1.0230x over previous
//
#include <hip/hip_runtime.h>

#define HDIM 96
#define LSTR 104   // LDS row stride in bf16 elems (96 + 8 pad); 208 B (16B-aligned rows)

typedef __attribute__((ext_vector_type(8))) short bf16x8;   // 8 bf16 = 4 VGPRs
typedef __attribute__((ext_vector_type(4))) float f32x4;

__device__ __forceinline__ unsigned short bf16rne(float x) {
  const unsigned u = __float_as_uint(x);
  return (unsigned short)((u + 0x7fff + ((u >> 16) & 1)) >> 16);
}

// fp32 -> (hi, lo) truncated bf16 pair; x ~= hi + lo with ~2^-16 rel error
__device__ __forceinline__ void split2(float x, unsigned short& hi, unsigned short& lo) {
  const unsigned u = __float_as_uint(x);
  hi = (unsigned short)(u >> 16);
  const float xhi = __uint_as_float(u & 0xffff0000u);
  lo = (unsigned short)(__float_as_uint(x - xhi) >> 16);
}

__global__ void zero_k(int* __restrict__ p, int n) {
  int i = blockIdx.x * blockDim.x + threadIdx.x;
  if (i < n) p[i] = 0;
}

__global__ void deg_rank_k(const int* __restrict__ dst, int* __restrict__ indeg,
                           int* __restrict__ rank, int e) {
  int i = blockIdx.x * blockDim.x + threadIdx.x;
  if (i < e) rank[i] = atomicAdd(&indeg[dst[i]], 1);
}

__device__ __forceinline__ int wave_incl_scan(int v, int lane) {
#pragma unroll
  for (int off = 1; off < 64; off <<= 1) {
    int t = __shfl_up(v, off, 64);
    if (lane >= off) v += t;
  }
  return v;
}

// Phase A (blocks [0,nb)): bsum[b] = chunk sum of indeg.
// Blocks [nb, ...): pre-split all 5 weight tiles into bf16 hi/lo, [n][k] layout
// (tile 0=W_local,1=W_g1,2=W_g2,3/4=W_fuse halves) — independent work fused
// into this launch to save a dispatch.
__global__ __launch_bounds__(1024) void scan_a_split_k(
    const int* __restrict__ indeg, int* __restrict__ bsum, int n, int nb,
    const float* __restrict__ W0, const float* __restrict__ W1,
    const float* __restrict__ W2, const float* __restrict__ W3,
    unsigned short* __restrict__ dH, unsigned short* __restrict__ dL) {
  const int tid = threadIdx.x;
  if (blockIdx.x >= nb) {   // ---- split_w part ----
    const int t = (blockIdx.x - nb) * 1024 + tid;
    if (t < 5 * 9216) {
      const int tile = t / 9216, r = t % 9216;
      const int nn = r / 96, k = r % 96;
      const float* W = (tile == 0) ? W0 : (tile == 1) ? W1 : (tile == 2) ? W2 : W3;
      const int row = (tile == 4) ? 96 + k : k;
      unsigned short h, l;
      split2(W[row * 96 + nn], h, l);
      dH[t] = h;
      dL[t] = l;
    }
    return;
  }
  // ---- scan_a part ----
  __shared__ int ws[16];
  const int i = blockIdx.x * 1024 + tid;
  int v = (i < n) ? indeg[i] : 0;
#pragma unroll
  for (int off = 32; off; off >>= 1) v += __shfl_down(v, off, 64);
  if ((tid & 63) == 0) ws[tid >> 6] = v;
  __syncthreads();
  if (tid < 16) {
    int s = ws[tid];
#pragma unroll
    for (int off = 8; off; off >>= 1) s += __shfl_down(s, off, 16);
    if (tid == 0) bsum[blockIdx.x] = s;
  }
}

__global__ __launch_bounds__(1024) void scan_b_k(const int* __restrict__ bsum,
                                                 int* __restrict__ bbase,
                                                 int* __restrict__ offsets, int nb, int n) {
  __shared__ int ws[16];
  const int tid = threadIdx.x, lane = tid & 63, w = tid >> 6;
  const int v = (tid < nb) ? bsum[tid] : 0;
  int incl = wave_incl_scan(v, lane);
  if (lane == 63) ws[w] = incl;
  __syncthreads();
  if (tid < 16) {
    int s = ws[tid];
#pragma unroll
    for (int off = 1; off < 16; off <<= 1) {
      int t = __shfl_up(s, off, 16);
      if (tid >= off) s += t;
    }
    ws[tid] = s;
  }
  __syncthreads();
  incl += (w > 0 ? ws[w - 1] : 0);
  if (tid < nb) bbase[tid] = incl - v;
  if (tid == 0) offsets[n] = ws[15];
}

__global__ __launch_bounds__(1024) void scan_c_k(const int* __restrict__ indeg,
                                                 const int* __restrict__ bbase,
                                                 int* __restrict__ offsets,
                                                 float* __restrict__ dis, int n) {
  __shared__ int ws[16];
  const int tid = threadIdx.x, lane = tid & 63, w = tid >> 6;
  const int i = blockIdx.x * 1024 + tid;
  const int v = (i < n) ? indeg[i] : 0;
  int incl = wave_incl_scan(v, lane);
  if (lane == 63) ws[w] = incl;
  __syncthreads();
  if (tid < 16) {
    int s = ws[tid];
#pragma unroll
    for (int off = 1; off < 16; off <<= 1) {
      int t = __shfl_up(s, off, 16);
      if (tid >= off) s += t;
    }
    ws[tid] = s;
  }
  __syncthreads();
  incl += (w > 0 ? ws[w - 1] : 0);
  if (i < n) {
    offsets[i] = bbase[blockIdx.x] + incl - v;
    dis[i] = rsqrtf((float)(1 + v));
  }
}

// Blocks [0,pb): CSR placement (atomic-free slot; fire-and-forget atomicExch).
// Blocks [pb,...): msgX = bf16(dis*x) — both depend only on scan_c; fused launch.
__global__ __launch_bounds__(256) void place_scale_k(
    const int* __restrict__ src, const int* __restrict__ dst,
    const int* __restrict__ rank, const int* __restrict__ offsets,
    int* __restrict__ csr_src, int e, int pb,
    const float* __restrict__ x, const float* __restrict__ dis,
    unsigned short* __restrict__ o, int n) {
  if (blockIdx.x < pb) {
    int i = blockIdx.x * 256 + threadIdx.x;
    if (i >= e) return;
    int d = dst[i];
    atomicExch(&csr_src[offsets[d] + rank[i]], src[i]);
  } else {
    int t = (blockIdx.x - pb) * 256 + threadIdx.x;
    if (t >= n * 24) return;
    const float d = dis[t / 24];
    float4 v = ((const float4*)x)[t];
    ushort4 h;
    h.x = bf16rne(v.x * d); h.y = bf16rne(v.y * d);
    h.z = bf16rne(v.z * d); h.w = bf16rne(v.w * d);
    ((ushort4*)o)[t] = h;
  }
}

__device__ __forceinline__ void acc8(float* a, uint4 p) {
  a[0] += __uint_as_float(p.x << 16);
  a[1] += __uint_as_float(p.x & 0xffff0000u);
  a[2] += __uint_as_float(p.y << 16);
  a[3] += __uint_as_float(p.y & 0xffff0000u);
  a[4] += __uint_as_float(p.z << 16);
  a[5] += __uint_as_float(p.z & 0xffff0000u);
  a[6] += __uint_as_float(p.w << 16);
  a[7] += __uint_as_float(p.w & 0xffff0000u);
}

// ---- fused gather + split-bf16 MFMA GEMM (R13 structure, unroll x4) ----
// 64 nodes/block: agg[d] = dis[d]*(hp[d] + sum hp[s]) gathered so each thread's
// fp32 accumulator IS its MFMA A-fragment (node=row0+16wv+m, k=32kc+8quad+j).
// Edge loop unrolled x4 with all 12 uint4 loads issued before accumulation —
// doubles in-flight memory per wave vs x2 (the hop kernels are latency-bound:
// R15 showed more waves alone does NOT help). LDS holds only W hi/lo (39.9 KB).
template<bool DUAL>
__global__ __launch_bounds__(256) void gat_gemm_k(
    const int* __restrict__ csr_src, const int* __restrict__ offsets,
    const float* __restrict__ dis, const unsigned short* __restrict__ hp,
    const unsigned short* __restrict__ WH0, const unsigned short* __restrict__ WL0,
    const float* __restrict__ b0,
    const unsigned short* __restrict__ WH1, const unsigned short* __restrict__ WL1,
    const float* __restrict__ b1,
    unsigned short* __restrict__ outH, unsigned short* __restrict__ outL,
    unsigned short* __restrict__ outMsg, int M) {
  __shared__ __align__(16) unsigned short Wh[96 * LSTR], Wl[96 * LSTR];
  const int t = threadIdx.x;
  const int lane = t & 63, wv = t >> 6;
  const int m = lane & 15, quad = lane >> 4;
  const int row0 = blockIdx.x * 64;
  const int node = row0 + 16 * wv + m;

  // stage W set0 (pure uint4 copies)
  for (int u = t; u < 1152; u += 256) {
    const int nn = u / 12, kq = u % 12;
    *(uint4*)(&Wh[nn * LSTR + 8 * kq]) = ((const uint4*)(WH0 + (size_t)nn * HDIM))[kq];
    *(uint4*)(&Wl[nn * LSTR + 8 * kq]) = ((const uint4*)(WL0 + (size_t)nn * HDIM))[kq];
  }

  // gather: a[kc][jj] accumulates k = 32*kc + 8*quad + jj  (== A-frag layout)
  float a[3][8];
#pragma unroll
  for (int c = 0; c < 3; c++)
#pragma unroll
    for (int jj = 0; jj < 8; jj++) a[c][jj] = 0.f;
  if (node < M) {
    const unsigned short* selfp = hp + (size_t)node * HDIM + 8 * quad;
    acc8(a[0], *(const uint4*)(selfp));
    acc8(a[1], *(const uint4*)(selfp + 32));
    acc8(a[2], *(const uint4*)(selfp + 64));
    int i = offsets[node];
    const int end = offsets[node + 1];
    for (; i + 3 < end; i += 4) {
      const int s0 = csr_src[i], s1 = csr_src[i + 1];
      const int s2 = csr_src[i + 2], s3 = csr_src[i + 3];
      const unsigned short* p0 = hp + (size_t)s0 * HDIM + 8 * quad;
      const unsigned short* p1 = hp + (size_t)s1 * HDIM + 8 * quad;
      const unsigned short* p2 = hp + (size_t)s2 * HDIM + 8 * quad;
      const unsigned short* p3 = hp + (size_t)s3 * HDIM + 8 * quad;
      // issue all 12 loads, then accumulate (keeps 12 in flight per wave)
      const uint4 v00 = *(const uint4*)(p0), v01 = *(const uint4*)(p0 + 32), v02 = *(const uint4*)(p0 + 64);
      const uint4 v10 = *(const uint4*)(p1), v11 = *(const uint4*)(p1 + 32), v12 = *(const uint4*)(p1 + 64);
      const uint4 v20 = *(const uint4*)(p2), v21 = *(const uint4*)(p2 + 32), v22 = *(const uint4*)(p2 + 64);
      const uint4 v30 = *(const uint4*)(p3), v31 = *(const uint4*)(p3 + 32), v32 = *(const uint4*)(p3 + 64);
      acc8(a[0], v00); acc8(a[1], v01); acc8(a[2], v02);
      acc8(a[0], v10); acc8(a[1], v11); acc8(a[2], v12);
      acc8(a[0], v20); acc8(a[1], v21); acc8(a[2], v22);
      acc8(a[0], v30); acc8(a[1], v31); acc8(a[2], v32);
    }
    for (; i < end; i++) {
      const unsigned short* p0 = hp + (size_t)csr_src[i] * HDIM + 8 * quad;
      acc8(a[0], *(const uint4*)(p0));
      acc8(a[1], *(const uint4*)(p0 + 32));
      acc8(a[2], *(const uint4*)(p0 + 64));
    }
    const float dd = dis[node];
#pragma unroll
    for (int c = 0; c < 3; c++)
#pragma unroll
      for (int jj = 0; jj < 8; jj++) a[c][jj] *= dd;
  }
  // split to A fragments in registers
  bf16x8 ah[3], al[3];
#pragma unroll
  for (int c = 0; c < 3; c++)
#pragma unroll
    for (int jj = 0; jj < 8; jj++) {
      unsigned short h, l;
      split2(a[c][jj], h, l);
      ah[c][jj] = (short)h;
      al[c][jj] = (short)l;
    }

  __syncthreads();   // W set0 visible

  f32x4 acc0[6];
#pragma unroll
  for (int c = 0; c < 6; c++) acc0[c] = (f32x4){0.f, 0.f, 0.f, 0.f};
#pragma unroll
  for (int kc = 0; kc < 3; kc++) {
    const int ko = 32 * kc + 8 * quad;
#pragma unroll
    for (int c = 0; c < 6; c++) {
      const bf16x8 wh = *(const bf16x8*)(&Wh[(16 * c + m) * LSTR + ko]);
      const bf16x8 wl = *(const bf16x8*)(&Wl[(16 * c + m) * LSTR + ko]);
      acc0[c] = __builtin_amdgcn_mfma_f32_16x16x32_bf16(ah[kc], wh, acc0[c], 0, 0, 0);
      acc0[c] = __builtin_amdgcn_mfma_f32_16x16x32_bf16(ah[kc], wl, acc0[c], 0, 0, 0);
      acc0[c] = __builtin_amdgcn_mfma_f32_16x16x32_bf16(al[kc], wh, acc0[c], 0, 0, 0);
    }
  }

  // epilogue set0: relu -> split pair.  D: col=16c+m, row = row0+16wv+4quad+r
  const int rbase = row0 + 16 * wv + 4 * quad;
#pragma unroll
  for (int c = 0; c < 6; c++) {
    const int col = 16 * c + m;
    const float bv = b0[col];
#pragma unroll
    for (int r = 0; r < 4; r++) {
      const int row = rbase + r;
      if (row < M) {
        const float v = fmaxf(acc0[c][r] + bv, 0.f);
        unsigned short h, l;
        split2(v, h, l);
        const size_t idx = (size_t)row * HDIM + col;
        outH[idx] = h;
        outL[idx] = l;
      }
    }
  }

  if (DUAL) {
    __syncthreads();   // all waves done reading W set0
    for (int u = t; u < 1152; u += 256) {
      const int nn = u / 12, kq = u % 12;
      *(uint4*)(&Wh[nn * LSTR + 8 * kq]) = ((const uint4*)(WH1 + (size_t)nn * HDIM))[kq];
      *(uint4*)(&Wl[nn * LSTR + 8 * kq]) = ((const uint4*)(WL1 + (size_t)nn * HDIM))[kq];
    }
    __syncthreads();
    f32x4 acc1[6];
#pragma unroll
    for (int c = 0; c < 6; c++) acc1[c] = (f32x4){0.f, 0.f, 0.f, 0.f};
#pragma unroll
    for (int kc = 0; kc < 3; kc++) {
      const int ko = 32 * kc + 8 * quad;
#pragma unroll
      for (int c = 0; c < 6; c++) {
        const bf16x8 wh = *(const bf16x8*)(&Wh[(16 * c + m) * LSTR + ko]);
        const bf16x8 wl = *(const bf16x8*)(&Wl[(16 * c + m) * LSTR + ko]);
        acc1[c] = __builtin_amdgcn_mfma_f32_16x16x32_bf16(ah[kc], wh, acc1[c], 0, 0, 0);
        acc1[c] = __builtin_amdgcn_mfma_f32_16x16x32_bf16(ah[kc], wl, acc1[c], 0, 0, 0);
        acc1[c] = __builtin_amdgcn_mfma_f32_16x16x32_bf16(al[kc], wh, acc1[c], 0, 0, 0);
      }
    }
    float dv[4];
#pragma unroll
    for (int r = 0; r < 4; r++) dv[r] = (rbase + r < M) ? dis[rbase + r] : 0.f;
#pragma unroll
    for (int c = 0; c < 6; c++) {
      const int col = 16 * c + m;
      const float bv = b1[col];
#pragma unroll
      for (int r = 0; r < 4; r++) {
        const int row = rbase + r;
        if (row < M)
          outMsg[(size_t)row * HDIM + col] = bf16rne(fmaxf(acc1[c][r] + bv, 0.f) * dv[r]);
      }
    }
  }
}

// ---- concat GEMM (copy-only staging, pre-split A and W) ----
// out[M,96] = [A0|A1][M,192] @ Wfuse + bias, fp32 out.
__global__ __launch_bounds__(256) void gemm_concat_k(
    const unsigned short* __restrict__ AH0, const unsigned short* __restrict__ AL0,
    const unsigned short* __restrict__ AH1, const unsigned short* __restrict__ AL1,
    const unsigned short* __restrict__ WH, const unsigned short* __restrict__ WL,
    const float* __restrict__ bias, float* __restrict__ out, int M) {
  __shared__ __align__(16) unsigned short Ah[64 * LSTR], Al[64 * LSTR];
  __shared__ __align__(16) unsigned short Wh[96 * LSTR], Wl[96 * LSTR];
  const int t = threadIdx.x;
  const int lane = t & 63, wv = t >> 6;
  const int m = lane & 15, quad = lane >> 4;
  const int row0 = blockIdx.x * 64;

  f32x4 acc[6];
#pragma unroll
  for (int c = 0; c < 6; c++) acc[c] = (f32x4){0.f, 0.f, 0.f, 0.f};

  for (int kt = 0; kt < 2; kt++) {
    const unsigned short* AH = kt ? AH1 : AH0;
    const unsigned short* AL = kt ? AL1 : AL0;
    if (kt) __syncthreads();
    for (int u = t; u < 768; u += 256) {
      const int r = u / 12, kq = u % 12;
      uint4 vh = make_uint4(0, 0, 0, 0), vl = make_uint4(0, 0, 0, 0);
      if (row0 + r < M) {
        vh = ((const uint4*)(AH + (size_t)(row0 + r) * HDIM))[kq];
        vl = ((const uint4*)(AL + (size_t)(row0 + r) * HDIM))[kq];
      }
      *(uint4*)(&Ah[r * LSTR + 8 * kq]) = vh;
      *(uint4*)(&Al[r * LSTR + 8 * kq]) = vl;
    }
    const unsigned short* WHt = WH + (size_t)kt * 9216;
    const unsigned short* WLt = WL + (size_t)kt * 9216;
    for (int u = t; u < 1152; u += 256) {
      const int nn = u / 12, kq = u % 12;
      *(uint4*)(&Wh[nn * LSTR + 8 * kq]) = ((const uint4*)(WHt + (size_t)nn * HDIM))[kq];
      *(uint4*)(&Wl[nn * LSTR + 8 * kq]) = ((const uint4*)(WLt + (size_t)nn * HDIM))[kq];
    }
    __syncthreads();
#pragma unroll
    for (int kc = 0; kc < 3; kc++) {
      const int ko = 32 * kc + 8 * quad;
      const bf16x8 ah = *(const bf16x8*)(&Ah[(16 * wv + m) * LSTR + ko]);
      const bf16x8 al = *(const bf16x8*)(&Al[(16 * wv + m) * LSTR + ko]);
#pragma unroll
      for (int c = 0; c < 6; c++) {
        const bf16x8 wh = *(const bf16x8*)(&Wh[(16 * c + m) * LSTR + ko]);
        const bf16x8 wl = *(const bf16x8*)(&Wl[(16 * c + m) * LSTR + ko]);
        acc[c] = __builtin_amdgcn_mfma_f32_16x16x32_bf16(ah, wh, acc[c], 0, 0, 0);
        acc[c] = __builtin_amdgcn_mfma_f32_16x16x32_bf16(ah, wl, acc[c], 0, 0, 0);
        acc[c] = __builtin_amdgcn_mfma_f32_16x16x32_bf16(al, wh, acc[c], 0, 0, 0);
      }
    }
  }

  const int rbase = row0 + 16 * wv + 4 * quad;
#pragma unroll
  for (int c = 0; c < 6; c++) {
    const int col = 16 * c + m;
    const float bv = bias[col];
#pragma unroll
    for (int r = 0; r < 4; r++) {
      const int row = rbase + r;
      if (row < M) out[(size_t)row * HDIM + col] = acc[c][r] + bv;
    }
  }
}

extern "C" void kernel_launch(void* const* d_in, const int* in_sizes, int n_in,
                              void* d_out, int out_size, void* d_ws, size_t ws_size,
                              hipStream_t stream) {
  const float* x       = (const float*)d_in[0];
  const int*   edge    = (const int*)d_in[1];
  const float* W_local = (const float*)d_in[2];
  const float* b_local = (const float*)d_in[3];
  const float* W_g1    = (const float*)d_in[4];
  const float* b_g1    = (const float*)d_in[5];
  const float* W_g2    = (const float*)d_in[6];
  const float* b_g2    = (const float*)d_in[7];
  const float* W_fuse  = (const float*)d_in[8]; // [192, 96] row-major
  const float* b_fuse  = (const float*)d_in[9];
  float* out = (float*)d_out;

  const int n = in_sizes[0] / HDIM;
  const int e = in_sizes[1] / 2;
  const int* src = edge;
  const int* dst = edge + e;
  const int nb = (n + 1023) / 1024;

  char* ws = (char*)d_ws;
  auto alloc = [&](size_t bytes) { char* p = ws; ws += (bytes + 255) & ~(size_t)255; return p; };
  int*   indeg   = (int*)alloc((size_t)n * 4);
  float* dis     = (float*)alloc((size_t)n * 4);
  int*   offsets = (int*)alloc((size_t)(n + 1) * 4);
  int*   bsum    = (int*)alloc((size_t)nb * 4);
  int*   bbase   = (int*)alloc((size_t)nb * 4);
  int*   rank    = (int*)alloc((size_t)e * 4);
  int*   csr_src = (int*)alloc((size_t)e * 4);
  const size_t mat16 = (size_t)n * HDIM * 2;
  unsigned short* msgX = (unsigned short*)alloc(mat16);   // x' messages
  unsigned short* msgG = (unsigned short*)alloc(mat16);   // g1' messages
  unsigned short* locH = (unsigned short*)alloc(mat16);   // local hi/lo
  unsigned short* locL = (unsigned short*)alloc(mat16);
  unsigned short* g2H  = (unsigned short*)alloc(mat16);   // g2 hi/lo
  unsigned short* g2L  = (unsigned short*)alloc(mat16);
  unsigned short* wH   = (unsigned short*)alloc(5 * 9216 * 2);
  unsigned short* wL   = (unsigned short*)alloc(5 * 9216 * 2);

  zero_k<<<(n + 255) / 256, 256, 0, stream>>>(indeg, n);
  deg_rank_k<<<(e + 255) / 256, 256, 0, stream>>>(dst, indeg, rank, e);
  // scan phase A + (independent) weight pre-split in one launch
  scan_a_split_k<<<nb + 45, 1024, 0, stream>>>(indeg, bsum, n, nb,
                                               W_local, W_g1, W_g2, W_fuse, wH, wL);
  scan_b_k<<<1, 1024, 0, stream>>>(bsum, bbase, offsets, nb, n);
  scan_c_k<<<nb, 1024, 0, stream>>>(indeg, bbase, offsets, dis, n);
  // CSR placement + x-message scaling in one launch (both depend on scan_c)
  const int pb = (e + 255) / 256;
  const int sb = (n * 24 + 255) / 256;
  place_scale_k<<<pb + sb, 256, 0, stream>>>(src, dst, rank, offsets, csr_src, e, pb,
                                             x, dis, msgX, n);

  const int gb = (n + 63) / 64;

  // hop 1 fused: gather(x') -> ax frags; local = split(relu(ax@Wl+b)); g1' = msg(dis·relu(ax@Wg1+b))
  gat_gemm_k<true><<<gb, 256, 0, stream>>>(csr_src, offsets, dis, msgX,
                                           wH, wL, b_local,
                                           wH + 9216, wL + 9216, b_g1,
                                           locH, locL, msgG, n);
  // hop 2 fused: gather(g1') -> ag2 frags; g2 = split(relu(ag2@Wg2+b))
  gat_gemm_k<false><<<gb, 256, 0, stream>>>(csr_src, offsets, dis, msgG,
                                            wH + 2 * 9216, wL + 2 * 9216, b_g2,
                                            nullptr, nullptr, nullptr,
                                            g2H, g2L, nullptr, n);
  // out = [local | g2] @ W_fuse + b_fuse
  gemm_concat_k<<<gb, 256, 0, stream>>>(locH, locL, g2H, g2L,
                                        wH + 3 * 9216, wL + 3 * 9216, b_fuse, out, n);
}